// Round 1
// baseline (444.632 us; speedup 1.0000x reference)
//
#include <hip/hip_runtime.h>

// PTConv fused: out[i] = (sum_{e: dst=i} relu([x_src, pos_src-pos_dst] @ W1 + b1)) @ W2 + deg(i)*b2
// Pipeline: zero deg -> histogram -> scan (offsets+cursor) -> scatter (CSR src list) -> fused per-node kernel.

#define HIDDEN 128

__global__ void k_zero(int* __restrict__ p, int n) {
    int i = blockIdx.x * blockDim.x + threadIdx.x;
    if (i < n) p[i] = 0;
}

__global__ void k_hist(const int* __restrict__ dst, int* __restrict__ deg, int E) {
    int e = blockIdx.x * blockDim.x + threadIdx.x;
    if (e < E) atomicAdd(&deg[dst[e]], 1);
}

__global__ void k_scan(const int* __restrict__ deg, int* __restrict__ offsets,
                       int* __restrict__ cursor, int N, int E) {
    __shared__ int sums[1024];
    int t = threadIdx.x;
    const int per = (N + 1023) >> 10;
    int beg = t * per;
    int end = beg + per; if (end > N) end = N;
    int s = 0;
    for (int i = beg; i < end; ++i) s += deg[i];
    sums[t] = s;
    __syncthreads();
    for (int off = 1; off < 1024; off <<= 1) {
        int v = (t >= off) ? sums[t - off] : 0;
        __syncthreads();
        sums[t] += v;
        __syncthreads();
    }
    int run = (t == 0) ? 0 : sums[t - 1];
    for (int i = beg; i < end; ++i) {
        int d = deg[i];
        offsets[i] = run;
        cursor[i] = run;
        run += d;
    }
    if (t == 0) offsets[N] = E;
}

__global__ void k_scatter(const int* __restrict__ src, const int* __restrict__ dst,
                          int* __restrict__ cursor, int* __restrict__ csr, int E) {
    int e = blockIdx.x * blockDim.x + threadIdx.x;
    if (e < E) {
        int d = dst[e];
        int p = atomicAdd(&cursor[d], 1);
        csr[p] = src[e];
    }
}

__device__ __forceinline__ float bcast(float v, int l) {
    return __uint_as_float(__builtin_amdgcn_readlane(__float_as_uint(v), l));
}

__global__ void k_main(const float* __restrict__ x, const float* __restrict__ pos,
                       const float* __restrict__ W1, const float* __restrict__ b1,
                       const float* __restrict__ W2, const float* __restrict__ b2,
                       const int* __restrict__ offsets, const int* __restrict__ csr,
                       float* __restrict__ out, int N) {
    __shared__ float w2s[HIDDEN * HIDDEN];  // 64 KiB
    int tid = threadIdx.x;
    // stage W2 once per block (coalesced float4)
    for (int i = tid; i < HIDDEN * HIDDEN / 4; i += blockDim.x) {
        ((float4*)w2s)[i] = ((const float4*)W2)[i];
    }
    __syncthreads();

    int lane = tid & 63;
    int wid  = tid >> 6;
    int c0 = 2 * lane, c1 = c0 + 1;

    // per-lane W1/b1/b2 constants for channels c0,c1
    float w10a = W1[c0],            w10b = W1[c1];
    float w11a = W1[HIDDEN + c0],   w11b = W1[HIDDEN + c1];
    float w12a = W1[2*HIDDEN + c0], w12b = W1[2*HIDDEN + c1];
    float b1a = b1[c0], b1b = b1[c1];
    float b2a = b2[c0], b2b = b2[c1];

    for (int node = blockIdx.x * 4 + wid; node < N; node += gridDim.x * 4) {
        int beg = offsets[node];
        int end = offsets[node + 1];
        float2 pi = ((const float2*)pos)[node];
        float acc0 = 0.f, acc1 = 0.f;

        for (int t = beg; t < end; t += 64) {
            int cnt = end - t; if (cnt > 64) cnt = 64;
            float a = 0.f, dx = 0.f, dy = 0.f;
            if (lane < cnt) {
                int j = csr[t + lane];
                a = x[j];
                float2 pj = ((const float2*)pos)[j];
                dx = pj.x - pi.x;
                dy = pj.y - pi.y;
            }
            for (int e = 0; e < cnt; ++e) {
                float ae  = bcast(a, e);
                float dxe = bcast(dx, e);
                float dye = bcast(dy, e);
                float h0 = fmaf(dye, w12a, fmaf(dxe, w11a, fmaf(ae, w10a, b1a)));
                float h1 = fmaf(dye, w12b, fmaf(dxe, w11b, fmaf(ae, w10b, b1b)));
                acc0 += fmaxf(h0, 0.f);
                acc1 += fmaxf(h1, 0.f);
            }
        }

        // out[node][k] = sum_c agg[c] * W2[c][k] + deg*b2[k]; lane owns k = c0,c1
        float o0 = 0.f, o1 = 0.f;
        #pragma unroll 8
        for (int cp = 0; cp < 64; ++cp) {
            float aev = bcast(acc0, cp);   // agg channel 2*cp
            float aod = bcast(acc1, cp);   // agg channel 2*cp+1
            float2 w2e = *(const float2*)&w2s[(2*cp) * HIDDEN + c0];
            float2 w2o = *(const float2*)&w2s[(2*cp + 1) * HIDDEN + c0];
            o0 = fmaf(aev, w2e.x, o0); o1 = fmaf(aev, w2e.y, o1);
            o0 = fmaf(aod, w2o.x, o0); o1 = fmaf(aod, w2o.y, o1);
        }
        float degf = (float)(end - beg);
        float2 res;
        res.x = fmaf(degf, b2a, o0);
        res.y = fmaf(degf, b2b, o1);
        *(float2*)&out[node * HIDDEN + c0] = res;
    }
}

extern "C" void kernel_launch(void* const* d_in, const int* in_sizes, int n_in,
                              void* d_out, int out_size, void* d_ws, size_t ws_size,
                              hipStream_t stream) {
    const float* x   = (const float*)d_in[0];
    const float* pos = (const float*)d_in[1];
    const float* W1  = (const float*)d_in[2];
    const float* b1  = (const float*)d_in[3];
    const float* W2  = (const float*)d_in[4];
    const float* b2  = (const float*)d_in[5];
    const int*   ei  = (const int*)d_in[6];

    int N = in_sizes[0];        // x is [N,1]
    int E = in_sizes[6] / 2;    // edge_index is [2,E]
    const int* src = ei;
    const int* dst = ei + E;
    float* out = (float*)d_out;

    // workspace layout: deg[N] | offsets[N+1] | cursor[N] | csr[E]
    int* deg     = (int*)d_ws;
    int* offsets = deg + N;
    int* cursor  = offsets + (N + 1);
    int* csr     = cursor + N;

    k_zero<<<(N + 255) / 256, 256, 0, stream>>>(deg, N);
    k_hist<<<(E + 255) / 256, 256, 0, stream>>>(dst, deg, E);
    k_scan<<<1, 1024, 0, stream>>>(deg, offsets, cursor, N, E);
    k_scatter<<<(E + 255) / 256, 256, 0, stream>>>(src, dst, cursor, csr, E);
    k_main<<<1024, 256, 0, stream>>>(x, pos, W1, b1, W2, b2, offsets, csr, out, N);
}

// Round 2
// 187.344 us; speedup vs baseline: 2.3733x; 2.3733x over previous
//
#include <hip/hip_runtime.h>

// PTConv fused: out[i] = (sum_{e: dst=i} relu([x_src, pos_src-pos_dst] @ W1 + b1)) @ W2 + deg(i)*b2
// Pipeline: bucket (64 nodes) counting sort with LDS aggregation, then per-bucket
// fused kernel that counting-sorts locally in LDS and aggregates relu features,
// then in-place @W2 on d_out.

#define HIDDEN 128
#define EPB 8192      // edges per block for hist/scatter
#define NBMAX 4096    // max buckets (N <= 256K)
#define CAP 4096      // edges per LDS chunk in k_main

__device__ __forceinline__ float bcast(float v, int l) {
    return __uint_as_float(__builtin_amdgcn_readlane(__float_as_uint(v), l));
}

__global__ void k_zero(int* __restrict__ p, int n) {
    int i = blockIdx.x * blockDim.x + threadIdx.x;
    if (i < n) p[i] = 0;
}

__global__ __launch_bounds__(256) void k_bucket_hist(const int* __restrict__ dst,
                                                     int* __restrict__ bcnt, int E, int NB) {
    __shared__ int h[NBMAX];
    int tid = threadIdx.x;
    for (int i = tid; i < NB; i += 256) h[i] = 0;
    __syncthreads();
    int base = blockIdx.x * EPB;
    int lim = base + EPB; if (lim > E) lim = E;
    for (int i = base + tid; i < lim; i += 256) atomicAdd(&h[dst[i] >> 6], 1);
    __syncthreads();
    for (int i = tid; i < NB; i += 256) { int c = h[i]; if (c) atomicAdd(&bcnt[i], c); }
}

__global__ void k_scan2(const int* __restrict__ bcnt, int* __restrict__ boff,
                        int* __restrict__ bcur, int NB, int E) {
    __shared__ int sums[1024];
    int t = threadIdx.x;
    int per = (NB + 1023) >> 10;
    int beg = t * per;
    int end = beg + per; if (end > NB) end = NB; if (beg > NB) beg = NB;
    int s = 0;
    for (int i = beg; i < end; ++i) s += bcnt[i];
    sums[t] = s;
    __syncthreads();
    for (int off = 1; off < 1024; off <<= 1) {
        int v = (t >= off) ? sums[t - off] : 0;
        __syncthreads();
        sums[t] += v;
        __syncthreads();
    }
    int run = (t == 0) ? 0 : sums[t - 1];
    for (int i = beg; i < end; ++i) {
        int d = bcnt[i];
        boff[i] = run;
        bcur[i] = run;
        run += d;
    }
    if (t == 0) boff[NB] = E;
}

__global__ __launch_bounds__(256) void k_bucket_scatter(const int* __restrict__ src,
                                                        const int* __restrict__ dst,
                                                        int* __restrict__ bcur,
                                                        unsigned int* __restrict__ pairs,
                                                        int E, int NB) {
    __shared__ int h[NBMAX];
    __shared__ int hb[NBMAX];
    int tid = threadIdx.x;
    for (int i = tid; i < NB; i += 256) h[i] = 0;
    __syncthreads();
    int base = blockIdx.x * EPB;
    int lim = base + EPB; if (lim > E) lim = E;
    for (int i = base + tid; i < lim; i += 256) atomicAdd(&h[dst[i] >> 6], 1);
    __syncthreads();
    for (int i = tid; i < NB; i += 256) {
        int c = h[i];
        hb[i] = c ? atomicAdd(&bcur[i], c) : 0;
        h[i] = 0;
    }
    __syncthreads();
    for (int i = base + tid; i < lim; i += 256) {
        int d = dst[i];
        int bkt = d >> 6;
        int loc = atomicAdd(&h[bkt], 1);
        pairs[hb[bkt] + loc] = ((unsigned int)src[i] << 6) | (unsigned int)(d & 63);
    }
}

// One block per bucket of 64 nodes. Counting-sort the bucket's edges by local
// node id in LDS, then per-node wave-parallel relu-MLP aggregation.
__global__ __launch_bounds__(256) void k_main(const float* __restrict__ x,
                                              const float* __restrict__ pos,
                                              const float* __restrict__ W1,
                                              const float* __restrict__ b1,
                                              const int* __restrict__ boff,
                                              const unsigned int* __restrict__ pairs,
                                              float* __restrict__ agg,
                                              int* __restrict__ deg, int N) {
    __shared__ unsigned int raw[CAP];
    __shared__ int ssrc[CAP];
    __shared__ int cnt64[64];
    __shared__ int off65[65];
    __shared__ int cur64[64];

    int tid = threadIdx.x, lane = tid & 63, w = tid >> 6;
    int b = blockIdx.x;
    int n0 = b << 6;
    int e0 = boff[b], e1 = boff[b + 1];

    int c0 = 2 * lane;
    float w10a = W1[c0],              w10b = W1[c0 + 1];
    float w11a = W1[HIDDEN + c0],     w11b = W1[HIDDEN + c0 + 1];
    float w12a = W1[2 * HIDDEN + c0], w12b = W1[2 * HIDDEN + c0 + 1];
    float b1a = b1[c0], b1b = b1[c0 + 1];

    float acc0[16], acc1[16];
    int dga[16];
    #pragma unroll
    for (int s = 0; s < 16; ++s) { acc0[s] = 0.f; acc1[s] = 0.f; dga[s] = 0; }

    for (int cbeg = e0; cbeg < e1; cbeg += CAP) {
        int ccnt = e1 - cbeg; if (ccnt > CAP) ccnt = CAP;
        for (int i = tid; i < ccnt; i += 256) raw[i] = pairs[cbeg + i];
        if (tid < 64) cnt64[tid] = 0;
        __syncthreads();
        for (int i = tid; i < ccnt; i += 256) atomicAdd(&cnt64[raw[i] & 63u], 1);
        __syncthreads();
        if (w == 0) {
            int v = cnt64[lane];
            int sc = v;
            #pragma unroll
            for (int d = 1; d < 64; d <<= 1) {
                int u = __shfl_up(sc, d);
                if (lane >= d) sc += u;
            }
            off65[lane + 1] = sc;
            if (lane == 0) off65[0] = 0;
            cur64[lane] = sc - v;  // exclusive
        }
        __syncthreads();
        for (int i = tid; i < ccnt; i += 256) {
            unsigned int r = raw[i];
            int p = atomicAdd(&cur64[r & 63u], 1);
            ssrc[p] = (int)(r >> 6);
        }
        __syncthreads();
        #pragma unroll
        for (int s = 0; s < 16; ++s) {
            int l = w * 16 + s;
            int sb = off65[l], se = off65[l + 1];
            if (sb < se) {
                float2 pi = ((const float2*)pos)[n0 + l];
                dga[s] += se - sb;
                for (int t0 = sb; t0 < se; t0 += 64) {
                    int m = se - t0; if (m > 64) m = 64;
                    float a = 0.f, dx = 0.f, dy = 0.f;
                    if (lane < m) {
                        int j = ssrc[t0 + lane];
                        a = x[j];
                        float2 pj = ((const float2*)pos)[j];
                        dx = pj.x - pi.x;
                        dy = pj.y - pi.y;
                    }
                    for (int e = 0; e < m; ++e) {
                        float ae = bcast(a, e), dxe = bcast(dx, e), dye = bcast(dy, e);
                        float h0 = fmaf(dye, w12a, fmaf(dxe, w11a, fmaf(ae, w10a, b1a)));
                        float h1 = fmaf(dye, w12b, fmaf(dxe, w11b, fmaf(ae, w10b, b1b)));
                        acc0[s] += fmaxf(h0, 0.f);
                        acc1[s] += fmaxf(h1, 0.f);
                    }
                }
            }
        }
        __syncthreads();
    }

    #pragma unroll
    for (int s = 0; s < 16; ++s) {
        int l = w * 16 + s;
        int node = n0 + l;
        if (node < N) {
            ((float2*)&agg[(size_t)node * HIDDEN])[lane] = make_float2(acc0[s], acc1[s]);
            if (lane == 0) deg[node] = dga[s];
        }
    }
}

// In-place on d_out: row = row @ W2 + deg*b2. Two rows per wave iteration to
// amortize LDS reads of W2.
__global__ __launch_bounds__(256) void k_w2(float* __restrict__ agg,
                                            const float* __restrict__ W2,
                                            const float* __restrict__ b2,
                                            const int* __restrict__ deg, int N) {
    __shared__ float w2s[HIDDEN * HIDDEN];  // 64 KiB
    int tid = threadIdx.x;
    for (int i = tid; i < HIDDEN * HIDDEN / 4; i += 256)
        ((float4*)w2s)[i] = ((const float4*)W2)[i];
    __syncthreads();
    int lane = tid & 63, w = tid >> 6;
    int c0 = 2 * lane;
    float b2a = b2[c0], b2b = b2[c0 + 1];

    for (int row = (blockIdx.x * 4 + w) * 2; row < N; row += gridDim.x * 8) {
        bool two = (row + 1) < N;
        float2 va = ((float2*)&agg[(size_t)row * HIDDEN])[lane];
        float2 vb = two ? ((float2*)&agg[(size_t)(row + 1) * HIDDEN])[lane]
                        : make_float2(0.f, 0.f);
        float oa0 = 0.f, oa1 = 0.f, ob0 = 0.f, ob1 = 0.f;
        #pragma unroll 8
        for (int cp = 0; cp < 64; ++cp) {
            float a0 = bcast(va.x, cp), a1 = bcast(va.y, cp);
            float g0 = bcast(vb.x, cp), g1 = bcast(vb.y, cp);
            float2 w2e = *(const float2*)&w2s[(2 * cp) * HIDDEN + c0];
            float2 w2o = *(const float2*)&w2s[(2 * cp + 1) * HIDDEN + c0];
            oa0 = fmaf(a0, w2e.x, oa0); oa1 = fmaf(a0, w2e.y, oa1);
            oa0 = fmaf(a1, w2o.x, oa0); oa1 = fmaf(a1, w2o.y, oa1);
            ob0 = fmaf(g0, w2e.x, ob0); ob1 = fmaf(g0, w2e.y, ob1);
            ob0 = fmaf(g1, w2o.x, ob0); ob1 = fmaf(g1, w2o.y, ob1);
        }
        float dga = (float)deg[row];
        ((float2*)&agg[(size_t)row * HIDDEN])[lane] =
            make_float2(fmaf(dga, b2a, oa0), fmaf(dga, b2b, oa1));
        if (two) {
            float dgb = (float)deg[row + 1];
            ((float2*)&agg[(size_t)(row + 1) * HIDDEN])[lane] =
                make_float2(fmaf(dgb, b2a, ob0), fmaf(dgb, b2b, ob1));
        }
    }
}

extern "C" void kernel_launch(void* const* d_in, const int* in_sizes, int n_in,
                              void* d_out, int out_size, void* d_ws, size_t ws_size,
                              hipStream_t stream) {
    const float* x   = (const float*)d_in[0];
    const float* pos = (const float*)d_in[1];
    const float* W1  = (const float*)d_in[2];
    const float* b1  = (const float*)d_in[3];
    const float* W2  = (const float*)d_in[4];
    const float* b2  = (const float*)d_in[5];
    const int*   ei  = (const int*)d_in[6];

    int N = in_sizes[0];        // x is [N,1]
    int E = in_sizes[6] / 2;    // edge_index is [2,E]
    const int* src = ei;
    const int* dst = ei + E;
    float* out = (float*)d_out;

    int NB = (N + 63) >> 6;

    // workspace: bcnt[NB] | boff[NB+1] | bcur[NB] | deg[N] | pairs[E]
    int* bcnt = (int*)d_ws;
    int* boff = bcnt + NB;
    int* bcur = boff + NB + 1;
    int* deg  = bcur + NB;
    unsigned int* pairs = (unsigned int*)(deg + N);

    int gribs = (E + EPB - 1) / EPB;

    k_zero<<<(NB + 255) / 256, 256, 0, stream>>>(bcnt, NB);
    k_bucket_hist<<<gribs, 256, 0, stream>>>(dst, bcnt, E, NB);
    k_scan2<<<1, 1024, 0, stream>>>(bcnt, boff, bcur, NB, E);
    k_bucket_scatter<<<gribs, 256, 0, stream>>>(src, dst, bcur, pairs, E, NB);
    k_main<<<NB, 256, 0, stream>>>(x, pos, W1, b1, boff, pairs, out, deg, N);
    k_w2<<<512, 256, 0, stream>>>(out, W2, b2, deg, N);
}

// Round 3
// 179.009 us; speedup vs baseline: 2.4838x; 1.0466x over previous
//
#include <hip/hip_runtime.h>

// PTConv fused: out[i] = (sum_{e: dst=i} relu([x_src, pos_src-pos_dst] @ W1 + b1)) @ W2 + deg(i)*b2
// Pipeline: 32-node-bucket counting sort (LDS-aggregated hist/scatter), then per-bucket
// fused kernel: LDS counting-sort + feature staging, per-node wave-parallel relu-MLP
// aggregation with per-node effective bias, then in-place @W2 on d_out.

#define HIDDEN 128
#define EPB 8192       // edges per block for hist/scatter
#define NBMAX 4096     // max buckets
#define BNODES 32      // nodes per bucket
#define CAP 1536       // edges per LDS chunk in k_main

__device__ __forceinline__ float bcast(float v, int l) {
    return __uint_as_float(__builtin_amdgcn_readlane(__float_as_uint(v), l));
}

__global__ void k_zero(int* __restrict__ p, int n) {
    int i = blockIdx.x * blockDim.x + threadIdx.x;
    if (i < n) p[i] = 0;
}

__global__ __launch_bounds__(256) void k_bucket_hist(const int* __restrict__ dst,
                                                     int* __restrict__ bcnt, int E, int NB) {
    __shared__ int h[NBMAX];
    int tid = threadIdx.x;
    for (int i = tid; i < NB; i += 256) h[i] = 0;
    __syncthreads();
    int base = blockIdx.x * EPB;
    int lim = base + EPB; if (lim > E) lim = E;
    for (int i = base + tid; i < lim; i += 256) atomicAdd(&h[dst[i] >> 5], 1);
    __syncthreads();
    for (int i = tid; i < NB; i += 256) { int c = h[i]; if (c) atomicAdd(&bcnt[i], c); }
}

__global__ void k_scan2(const int* __restrict__ bcnt, int* __restrict__ boff,
                        int* __restrict__ bcur, int NB, int E) {
    __shared__ int sums[1024];
    int t = threadIdx.x;
    int per = (NB + 1023) >> 10;
    int beg = t * per;
    int end = beg + per; if (end > NB) end = NB; if (beg > NB) beg = NB;
    int s = 0;
    for (int i = beg; i < end; ++i) s += bcnt[i];
    sums[t] = s;
    __syncthreads();
    for (int off = 1; off < 1024; off <<= 1) {
        int v = (t >= off) ? sums[t - off] : 0;
        __syncthreads();
        sums[t] += v;
        __syncthreads();
    }
    int run = (t == 0) ? 0 : sums[t - 1];
    for (int i = beg; i < end; ++i) {
        int d = bcnt[i];
        boff[i] = run;
        bcur[i] = run;
        run += d;
    }
    if (t == 0) boff[NB] = E;
}

__global__ __launch_bounds__(256) void k_bucket_scatter(const int* __restrict__ src,
                                                        const int* __restrict__ dst,
                                                        int* __restrict__ bcur,
                                                        unsigned int* __restrict__ pairs,
                                                        int E, int NB) {
    __shared__ int h[NBMAX];
    __shared__ int hb[NBMAX];
    int tid = threadIdx.x;
    for (int i = tid; i < NB; i += 256) h[i] = 0;
    __syncthreads();
    int base = blockIdx.x * EPB;
    int lim = base + EPB; if (lim > E) lim = E;
    for (int i = base + tid; i < lim; i += 256) atomicAdd(&h[dst[i] >> 5], 1);
    __syncthreads();
    for (int i = tid; i < NB; i += 256) {
        int c = h[i];
        hb[i] = c ? atomicAdd(&bcur[i], c) : 0;
        h[i] = 0;
    }
    __syncthreads();
    for (int i = base + tid; i < lim; i += 256) {
        int d = dst[i];
        int bkt = d >> 5;
        int loc = atomicAdd(&h[bkt], 1);
        pairs[hb[bkt] + loc] = ((unsigned int)src[i] << 5) | (unsigned int)(d & 31);
    }
}

// One block per bucket of 32 nodes. Counting-sort edges by local node id in LDS,
// staging (x, pos) features at the sorted position; then per-node wave-parallel
// relu-MLP aggregation reading LDS broadcasts.
__global__ __launch_bounds__(256) void k_main(const float* __restrict__ x,
                                              const float* __restrict__ pos,
                                              const float* __restrict__ W1,
                                              const float* __restrict__ b1,
                                              const int* __restrict__ boff,
                                              const unsigned int* __restrict__ pairs,
                                              float* __restrict__ agg,
                                              int* __restrict__ deg, int N) {
    __shared__ unsigned int raw[CAP];
    __shared__ float a_s[CAP];
    __shared__ float2 p_s[CAP];
    __shared__ int cnt[BNODES];
    __shared__ int offn[BNODES + 1];
    __shared__ int cur[BNODES];

    int tid = threadIdx.x, lane = tid & 63, w = tid >> 6;
    int b = blockIdx.x;
    int n0 = b * BNODES;
    int e0 = boff[b], e1 = boff[b + 1];

    int c0 = 2 * lane;
    float w10a = W1[c0],              w10b = W1[c0 + 1];
    float w11a = W1[HIDDEN + c0],     w11b = W1[HIDDEN + c0 + 1];
    float w12a = W1[2 * HIDDEN + c0], w12b = W1[2 * HIDDEN + c0 + 1];
    float b1a = b1[c0], b1b = b1[c0 + 1];

    float acc0[8], acc1[8];
    int dga[8];
    #pragma unroll
    for (int s = 0; s < 8; ++s) { acc0[s] = 0.f; acc1[s] = 0.f; dga[s] = 0; }

    for (int cbeg = e0; cbeg < e1; cbeg += CAP) {
        int ccnt = e1 - cbeg; if (ccnt > CAP) ccnt = CAP;
        for (int i = tid; i < ccnt; i += 256) raw[i] = pairs[cbeg + i];
        if (tid < BNODES) cnt[tid] = 0;
        __syncthreads();
        for (int i = tid; i < ccnt; i += 256) atomicAdd(&cnt[raw[i] & 31u], 1);
        __syncthreads();
        if (tid < BNODES) {
            int v = cnt[tid];
            int sc = v;
            #pragma unroll
            for (int d = 1; d < BNODES; d <<= 1) {
                int u = __shfl_up(sc, d);
                if (lane >= d) sc += u;
            }
            offn[tid + 1] = sc;
            if (tid == 0) offn[0] = 0;
            cur[tid] = sc - v;  // exclusive
        }
        __syncthreads();
        for (int i = tid; i < ccnt; i += 256) {
            unsigned int r = raw[i];
            int j = (int)(r >> 5);
            int p = atomicAdd(&cur[r & 31u], 1);
            a_s[p] = x[j];
            p_s[p] = ((const float2*)pos)[j];
        }
        __syncthreads();
        #pragma unroll
        for (int s = 0; s < 8; ++s) {
            int l = w * 8 + s;
            int sb = offn[l], se = offn[l + 1];
            if (sb < se) {
                float2 pi = ((const float2*)pos)[n0 + l];
                dga[s] += se - sb;
                // effective bias: b1 - px_i*w1row1 - py_i*w1row2
                float bba = b1a - pi.x * w11a - pi.y * w12a;
                float bbb = b1b - pi.x * w11b - pi.y * w12b;
                float A0 = acc0[s], A1 = acc1[s];
                #pragma unroll 4
                for (int t = sb; t < se; ++t) {
                    float ae = a_s[t];
                    float2 pj = p_s[t];
                    float h0 = fmaf(pj.y, w12a, fmaf(pj.x, w11a, fmaf(ae, w10a, bba)));
                    float h1 = fmaf(pj.y, w12b, fmaf(pj.x, w11b, fmaf(ae, w10b, bbb)));
                    A0 += fmaxf(h0, 0.f);
                    A1 += fmaxf(h1, 0.f);
                }
                acc0[s] = A0; acc1[s] = A1;
            }
        }
        __syncthreads();
    }

    #pragma unroll
    for (int s = 0; s < 8; ++s) {
        int l = w * 8 + s;
        int node = n0 + l;
        if (node < N) {
            ((float2*)&agg[(size_t)node * HIDDEN])[lane] = make_float2(acc0[s], acc1[s]);
            if (lane == 0) deg[node] = dga[s];
        }
    }
}

// In-place on d_out: row = row @ W2 + deg*b2. Two rows per wave iteration.
__global__ __launch_bounds__(256) void k_w2(float* __restrict__ agg,
                                            const float* __restrict__ W2,
                                            const float* __restrict__ b2,
                                            const int* __restrict__ deg, int N) {
    __shared__ float w2s[HIDDEN * HIDDEN];  // 64 KiB
    int tid = threadIdx.x;
    for (int i = tid; i < HIDDEN * HIDDEN / 4; i += 256)
        ((float4*)w2s)[i] = ((const float4*)W2)[i];
    __syncthreads();
    int lane = tid & 63, w = tid >> 6;
    int c0 = 2 * lane;
    float b2a = b2[c0], b2b = b2[c0 + 1];

    for (int row = (blockIdx.x * 4 + w) * 2; row < N; row += gridDim.x * 8) {
        bool two = (row + 1) < N;
        float2 va = ((float2*)&agg[(size_t)row * HIDDEN])[lane];
        float2 vb = two ? ((float2*)&agg[(size_t)(row + 1) * HIDDEN])[lane]
                        : make_float2(0.f, 0.f);
        float oa0 = 0.f, oa1 = 0.f, ob0 = 0.f, ob1 = 0.f;
        #pragma unroll 8
        for (int cp = 0; cp < 64; ++cp) {
            float a0 = bcast(va.x, cp), a1 = bcast(va.y, cp);
            float g0 = bcast(vb.x, cp), g1 = bcast(vb.y, cp);
            float2 w2e = *(const float2*)&w2s[(2 * cp) * HIDDEN + c0];
            float2 w2o = *(const float2*)&w2s[(2 * cp + 1) * HIDDEN + c0];
            oa0 = fmaf(a0, w2e.x, oa0); oa1 = fmaf(a0, w2e.y, oa1);
            oa0 = fmaf(a1, w2o.x, oa0); oa1 = fmaf(a1, w2o.y, oa1);
            ob0 = fmaf(g0, w2e.x, ob0); ob1 = fmaf(g0, w2e.y, ob1);
            ob0 = fmaf(g1, w2o.x, ob0); ob1 = fmaf(g1, w2o.y, ob1);
        }
        float dga = (float)deg[row];
        ((float2*)&agg[(size_t)row * HIDDEN])[lane] =
            make_float2(fmaf(dga, b2a, oa0), fmaf(dga, b2b, oa1));
        if (two) {
            float dgb = (float)deg[row + 1];
            ((float2*)&agg[(size_t)(row + 1) * HIDDEN])[lane] =
                make_float2(fmaf(dgb, b2a, ob0), fmaf(dgb, b2b, ob1));
        }
    }
}

extern "C" void kernel_launch(void* const* d_in, const int* in_sizes, int n_in,
                              void* d_out, int out_size, void* d_ws, size_t ws_size,
                              hipStream_t stream) {
    const float* x   = (const float*)d_in[0];
    const float* pos = (const float*)d_in[1];
    const float* W1  = (const float*)d_in[2];
    const float* b1  = (const float*)d_in[3];
    const float* W2  = (const float*)d_in[4];
    const float* b2  = (const float*)d_in[5];
    const int*   ei  = (const int*)d_in[6];

    int N = in_sizes[0];        // x is [N,1]
    int E = in_sizes[6] / 2;    // edge_index is [2,E]
    const int* src = ei;
    const int* dst = ei + E;
    float* out = (float*)d_out;

    int NB = (N + BNODES - 1) / BNODES;

    // workspace: bcnt[NB] | boff[NB+1] | bcur[NB] | deg[N] | pairs[E]
    int* bcnt = (int*)d_ws;
    int* boff = bcnt + NB;
    int* bcur = boff + NB + 1;
    int* deg  = bcur + NB;
    unsigned int* pairs = (unsigned int*)(deg + N);

    int gribs = (E + EPB - 1) / EPB;

    k_zero<<<(NB + 255) / 256, 256, 0, stream>>>(bcnt, NB);
    k_bucket_hist<<<gribs, 256, 0, stream>>>(dst, bcnt, E, NB);
    k_scan2<<<1, 1024, 0, stream>>>(bcnt, boff, bcur, NB, E);
    k_bucket_scatter<<<gribs, 256, 0, stream>>>(src, dst, bcur, pairs, E, NB);
    k_main<<<NB, 256, 0, stream>>>(x, pos, W1, b1, boff, pairs, out, deg, N);
    k_w2<<<512, 256, 0, stream>>>(out, W2, b2, deg, N);
}

// Round 4
// 155.055 us; speedup vs baseline: 2.8676x; 1.1545x over previous
//
#include <hip/hip_runtime.h>

// PTConv fused: out[i] = (sum_{e: dst=i} relu([x_src, pos_src-pos_dst] @ W1 + b1)) @ W2 + deg(i)*b2
// Pipeline: 32-node-bucket counting sort (LDS-aggregated hist/scatter, EPB=16K),
// per-bucket fused kernel (LDS sort + feature staging + packed-f32 relu-MLP
// aggregation with per-node effective bias), then in-place @W2 on d_out.

#define HIDDEN 128
#define EPB 16384      // edges per block for hist/scatter
#define SThr 512       // threads for hist/scatter
#define NBMAX 4096     // max buckets
#define BNODES 32      // nodes per bucket
#define CAP 2048       // edges per LDS chunk in k_main

typedef float v2f __attribute__((ext_vector_type(2)));

__device__ __forceinline__ float bcast(float v, int l) {
    return __uint_as_float(__builtin_amdgcn_readlane(__float_as_uint(v), l));
}

__global__ void k_zero(int* __restrict__ p, int n) {
    int i = blockIdx.x * blockDim.x + threadIdx.x;
    if (i < n) p[i] = 0;
}

__global__ __launch_bounds__(SThr) void k_bucket_hist(const int* __restrict__ dst,
                                                      int* __restrict__ bcnt, int E, int NB) {
    __shared__ int h[NBMAX];
    int tid = threadIdx.x;
    for (int i = tid; i < NB; i += SThr) h[i] = 0;
    __syncthreads();
    int base = blockIdx.x * EPB;
    int lim = base + EPB; if (lim > E) lim = E;
    for (int i = base + tid; i < lim; i += SThr) atomicAdd(&h[dst[i] >> 5], 1);
    __syncthreads();
    for (int i = tid; i < NB; i += SThr) { int c = h[i]; if (c) atomicAdd(&bcnt[i], c); }
}

__global__ void k_scan2(const int* __restrict__ bcnt, int* __restrict__ boff,
                        int* __restrict__ bcur, int NB, int E) {
    __shared__ int sums[1024];
    int t = threadIdx.x;
    int per = (NB + 1023) >> 10;
    int beg = t * per;
    int end = beg + per; if (end > NB) end = NB; if (beg > NB) beg = NB;
    int s = 0;
    for (int i = beg; i < end; ++i) s += bcnt[i];
    sums[t] = s;
    __syncthreads();
    for (int off = 1; off < 1024; off <<= 1) {
        int v = (t >= off) ? sums[t - off] : 0;
        __syncthreads();
        sums[t] += v;
        __syncthreads();
    }
    int run = (t == 0) ? 0 : sums[t - 1];
    for (int i = beg; i < end; ++i) {
        int d = bcnt[i];
        boff[i] = run;
        bcur[i] = run;
        run += d;
    }
    if (t == 0) boff[NB] = E;
}

__global__ __launch_bounds__(SThr) void k_bucket_scatter(const int* __restrict__ src,
                                                         const int* __restrict__ dst,
                                                         int* __restrict__ bcur,
                                                         unsigned int* __restrict__ pairs,
                                                         int E, int NB) {
    __shared__ int h[NBMAX];
    __shared__ int hb[NBMAX];
    int tid = threadIdx.x;
    for (int i = tid; i < NB; i += SThr) h[i] = 0;
    __syncthreads();
    int base = blockIdx.x * EPB;
    int lim = base + EPB; if (lim > E) lim = E;
    for (int i = base + tid; i < lim; i += SThr) atomicAdd(&h[dst[i] >> 5], 1);
    __syncthreads();
    for (int i = tid; i < NB; i += SThr) {
        int c = h[i];
        hb[i] = c ? atomicAdd(&bcur[i], c) : 0;
        h[i] = 0;
    }
    __syncthreads();
    for (int i = base + tid; i < lim; i += SThr) {
        int d = dst[i];
        int bkt = d >> 5;
        int loc = atomicAdd(&h[bkt], 1);
        pairs[hb[bkt] + loc] = ((unsigned int)src[i] << 5) | (unsigned int)(d & 31);
    }
}

// One block per bucket of 32 nodes. Counting-sort edges by local node id in LDS,
// staging (x, pos) features at the sorted position; then per-node wave-parallel
// relu-MLP aggregation (2 channels/lane, packed f32 math) reading LDS broadcasts.
__global__ __launch_bounds__(256) void k_main(const float* __restrict__ x,
                                              const float* __restrict__ pos,
                                              const float* __restrict__ W1,
                                              const float* __restrict__ b1,
                                              const int* __restrict__ boff,
                                              const unsigned int* __restrict__ pairs,
                                              float* __restrict__ agg,
                                              int* __restrict__ deg, int N) {
    __shared__ unsigned int raw[CAP];
    __shared__ float a_s[CAP];
    __shared__ v2f p_s[CAP];
    __shared__ int cnt[BNODES];
    __shared__ int offn[BNODES + 1];
    __shared__ int cur[BNODES];

    int tid = threadIdx.x, lane = tid & 63, w = tid >> 6;
    int b = blockIdx.x;
    int n0 = b * BNODES;
    int e0 = boff[b], e1 = boff[b + 1];

    int c0 = 2 * lane;
    v2f w10 = { W1[c0],              W1[c0 + 1] };
    v2f w11 = { W1[HIDDEN + c0],     W1[HIDDEN + c0 + 1] };
    v2f w12 = { W1[2 * HIDDEN + c0], W1[2 * HIDDEN + c0 + 1] };
    v2f b1v = { b1[c0], b1[c0 + 1] };
    const v2f zero = { 0.f, 0.f };

    v2f acc[8];
    int dga[8];
    #pragma unroll
    for (int s = 0; s < 8; ++s) { acc[s] = zero; dga[s] = 0; }

    for (int cbeg = e0; cbeg < e1; cbeg += CAP) {
        int ccnt = e1 - cbeg; if (ccnt > CAP) ccnt = CAP;
        for (int i = tid; i < ccnt; i += 256) raw[i] = pairs[cbeg + i];
        if (tid < BNODES) cnt[tid] = 0;
        __syncthreads();
        for (int i = tid; i < ccnt; i += 256) atomicAdd(&cnt[raw[i] & 31u], 1);
        __syncthreads();
        if (tid < BNODES) {
            int v = cnt[tid];
            int sc = v;
            #pragma unroll
            for (int d = 1; d < BNODES; d <<= 1) {
                int u = __shfl_up(sc, d);
                if (lane >= d) sc += u;
            }
            offn[tid + 1] = sc;
            if (tid == 0) offn[0] = 0;
            cur[tid] = sc - v;  // exclusive
        }
        __syncthreads();
        for (int i = tid; i < ccnt; i += 256) {
            unsigned int r = raw[i];
            int j = (int)(r >> 5);
            int p = atomicAdd(&cur[r & 31u], 1);
            a_s[p] = x[j];
            const float2 pj = ((const float2*)pos)[j];
            p_s[p] = (v2f){ pj.x, pj.y };
        }
        __syncthreads();
        #pragma unroll
        for (int s = 0; s < 8; ++s) {
            int l = w * 8 + s;
            int sb = offn[l], se = offn[l + 1];
            if (sb < se) {
                float2 pi = ((const float2*)pos)[n0 + l];
                dga[s] += se - sb;
                // effective bias: b1 - px_i*w1row1 - py_i*w1row2
                v2f bb = b1v - pi.x * w11 - pi.y * w12;
                v2f A = acc[s];
                #pragma unroll 4
                for (int t = sb; t < se; ++t) {
                    float ae = a_s[t];
                    v2f pj = p_s[t];
                    v2f h = ae * w10 + bb;
                    h = pj.x * w11 + h;
                    h = pj.y * w12 + h;
                    h = __builtin_elementwise_max(h, zero);
                    A += h;
                }
                acc[s] = A;
            }
        }
        __syncthreads();
    }

    #pragma unroll
    for (int s = 0; s < 8; ++s) {
        int l = w * 8 + s;
        int node = n0 + l;
        if (node < N) {
            ((v2f*)&agg[(size_t)node * HIDDEN])[lane] = acc[s];
            if (lane == 0) deg[node] = dga[s];
        }
    }
}

// In-place on d_out: row = row @ W2 + deg*b2. Two rows per wave iteration,
// packed f32 math on the 2 output channels per lane.
__global__ __launch_bounds__(256) void k_w2(float* __restrict__ agg,
                                            const float* __restrict__ W2,
                                            const float* __restrict__ b2,
                                            const int* __restrict__ deg, int N) {
    __shared__ float w2s[HIDDEN * HIDDEN];  // 64 KiB
    int tid = threadIdx.x;
    for (int i = tid; i < HIDDEN * HIDDEN / 4; i += 256)
        ((float4*)w2s)[i] = ((const float4*)W2)[i];
    __syncthreads();
    int lane = tid & 63, w = tid >> 6;
    int c0 = 2 * lane;
    v2f b2v = { b2[c0], b2[c0 + 1] };
    const v2f zero = { 0.f, 0.f };

    for (int row = (blockIdx.x * 4 + w) * 2; row < N; row += gridDim.x * 8) {
        bool two = (row + 1) < N;
        v2f va = ((v2f*)&agg[(size_t)row * HIDDEN])[lane];
        v2f vb = two ? ((v2f*)&agg[(size_t)(row + 1) * HIDDEN])[lane] : zero;
        v2f oa = zero, ob = zero;
        #pragma unroll 8
        for (int cp = 0; cp < 64; ++cp) {
            float a0 = bcast(va.x, cp), a1 = bcast(va.y, cp);
            float g0 = bcast(vb.x, cp), g1 = bcast(vb.y, cp);
            v2f w2e = *(const v2f*)&w2s[(2 * cp) * HIDDEN + c0];
            v2f w2o = *(const v2f*)&w2s[(2 * cp + 1) * HIDDEN + c0];
            oa = a0 * w2e + oa;
            oa = a1 * w2o + oa;
            ob = g0 * w2e + ob;
            ob = g1 * w2o + ob;
        }
        float dga = (float)deg[row];
        ((v2f*)&agg[(size_t)row * HIDDEN])[lane] = dga * b2v + oa;
        if (two) {
            float dgb = (float)deg[row + 1];
            ((v2f*)&agg[(size_t)(row + 1) * HIDDEN])[lane] = dgb * b2v + ob;
        }
    }
}

extern "C" void kernel_launch(void* const* d_in, const int* in_sizes, int n_in,
                              void* d_out, int out_size, void* d_ws, size_t ws_size,
                              hipStream_t stream) {
    const float* x   = (const float*)d_in[0];
    const float* pos = (const float*)d_in[1];
    const float* W1  = (const float*)d_in[2];
    const float* b1  = (const float*)d_in[3];
    const float* W2  = (const float*)d_in[4];
    const float* b2  = (const float*)d_in[5];
    const int*   ei  = (const int*)d_in[6];

    int N = in_sizes[0];        // x is [N,1]
    int E = in_sizes[6] / 2;    // edge_index is [2,E]
    const int* src = ei;
    const int* dst = ei + E;
    float* out = (float*)d_out;

    int NB = (N + BNODES - 1) / BNODES;

    // workspace: bcnt[NB] | boff[NB+1] | bcur[NB] | deg[N] | pairs[E]
    int* bcnt = (int*)d_ws;
    int* boff = bcnt + NB;
    int* bcur = boff + NB + 1;
    int* deg  = bcur + NB;
    unsigned int* pairs = (unsigned int*)(deg + N);

    int gribs = (E + EPB - 1) / EPB;

    k_zero<<<(NB + 255) / 256, 256, 0, stream>>>(bcnt, NB);
    k_bucket_hist<<<gribs, SThr, 0, stream>>>(dst, bcnt, E, NB);
    k_scan2<<<1, 1024, 0, stream>>>(bcnt, boff, bcur, NB, E);
    k_bucket_scatter<<<gribs, SThr, 0, stream>>>(src, dst, bcur, pairs, E, NB);
    k_main<<<NB, 256, 0, stream>>>(x, pos, W1, b1, boff, pairs, out, deg, N);
    k_w2<<<512, 256, 0, stream>>>(out, W2, b2, deg, N);
}

// Round 5
// 118.891 us; speedup vs baseline: 3.7398x; 1.3042x over previous
//
#include <hip/hip_runtime.h>

// PTConv fused: out[i] = (sum_{e: dst=i} relu([x_src, pos_src-pos_dst] @ W1 + b1)) @ W2 + deg(i)*b2
// Pipeline: 32-node-bucket counting sort (LDS-aggregated hist/scatter, EPB=16K),
// per-bucket fused kernel (LDS sort + feature staging + packed-f32 relu-MLP
// aggregation with per-node effective bias), then MFMA bf16 GEMM for @W2,
// in-place on d_out.

#define HIDDEN 128
#define EPB 16384      // edges per block for hist/scatter
#define SThr 512       // threads for hist/scatter
#define NBMAX 4096     // max buckets
#define BNODES 32      // nodes per bucket
#define CAP 2048       // edges per LDS chunk in k_main
#define W2LD 136       // padded leading dim for W2^T in LDS (bf16 elems)

typedef float v2f __attribute__((ext_vector_type(2)));
typedef short bf16x8 __attribute__((ext_vector_type(8)));
typedef float f32x4 __attribute__((ext_vector_type(4)));

__device__ __forceinline__ float bcast(float v, int l) {
    return __uint_as_float(__builtin_amdgcn_readlane(__float_as_uint(v), l));
}

__device__ __forceinline__ unsigned short f2bf(float f) {
    unsigned int u = __float_as_uint(f);
    u += 0x7fffu + ((u >> 16) & 1u);   // round-to-nearest-even
    return (unsigned short)(u >> 16);
}

__global__ void k_zero(int* __restrict__ p, int n) {
    int i = blockIdx.x * blockDim.x + threadIdx.x;
    if (i < n) p[i] = 0;
}

__global__ __launch_bounds__(SThr) void k_bucket_hist(const int* __restrict__ dst,
                                                      int* __restrict__ bcnt, int E, int NB) {
    __shared__ int h[NBMAX];
    int tid = threadIdx.x;
    for (int i = tid; i < NB; i += SThr) h[i] = 0;
    __syncthreads();
    int base = blockIdx.x * EPB;
    int lim = base + EPB; if (lim > E) lim = E;
    for (int i = base + tid; i < lim; i += SThr) atomicAdd(&h[dst[i] >> 5], 1);
    __syncthreads();
    for (int i = tid; i < NB; i += SThr) { int c = h[i]; if (c) atomicAdd(&bcnt[i], c); }
}

__global__ void k_scan2(const int* __restrict__ bcnt, int* __restrict__ boff,
                        int* __restrict__ bcur, int NB, int E) {
    __shared__ int sums[1024];
    int t = threadIdx.x;
    int per = (NB + 1023) >> 10;
    int beg = t * per;
    int end = beg + per; if (end > NB) end = NB; if (beg > NB) beg = NB;
    int s = 0;
    for (int i = beg; i < end; ++i) s += bcnt[i];
    sums[t] = s;
    __syncthreads();
    for (int off = 1; off < 1024; off <<= 1) {
        int v = (t >= off) ? sums[t - off] : 0;
        __syncthreads();
        sums[t] += v;
        __syncthreads();
    }
    int run = (t == 0) ? 0 : sums[t - 1];
    for (int i = beg; i < end; ++i) {
        int d = bcnt[i];
        boff[i] = run;
        bcur[i] = run;
        run += d;
    }
    if (t == 0) boff[NB] = E;
}

__global__ __launch_bounds__(SThr) void k_bucket_scatter(const int* __restrict__ src,
                                                         const int* __restrict__ dst,
                                                         int* __restrict__ bcur,
                                                         unsigned int* __restrict__ pairs,
                                                         int E, int NB) {
    __shared__ int h[NBMAX];
    __shared__ int hb[NBMAX];
    int tid = threadIdx.x;
    for (int i = tid; i < NB; i += SThr) h[i] = 0;
    __syncthreads();
    int base = blockIdx.x * EPB;
    int lim = base + EPB; if (lim > E) lim = E;
    for (int i = base + tid; i < lim; i += SThr) atomicAdd(&h[dst[i] >> 5], 1);
    __syncthreads();
    for (int i = tid; i < NB; i += SThr) {
        int c = h[i];
        hb[i] = c ? atomicAdd(&bcur[i], c) : 0;
        h[i] = 0;
    }
    __syncthreads();
    for (int i = base + tid; i < lim; i += SThr) {
        int d = dst[i];
        int bkt = d >> 5;
        int loc = atomicAdd(&h[bkt], 1);
        pairs[hb[bkt] + loc] = ((unsigned int)src[i] << 5) | (unsigned int)(d & 31);
    }
}

// One block per bucket of 32 nodes. Counting-sort edges by local node id in LDS,
// staging (x, pos) features at the sorted position; then per-node wave-parallel
// relu-MLP aggregation (2 channels/lane, packed f32 math) reading LDS broadcasts.
__global__ __launch_bounds__(256) void k_main(const float* __restrict__ x,
                                              const float* __restrict__ pos,
                                              const float* __restrict__ W1,
                                              const float* __restrict__ b1,
                                              const int* __restrict__ boff,
                                              const unsigned int* __restrict__ pairs,
                                              float* __restrict__ agg,
                                              int* __restrict__ deg, int N) {
    __shared__ unsigned int raw[CAP];
    __shared__ float a_s[CAP];
    __shared__ v2f p_s[CAP];
    __shared__ int cnt[BNODES];
    __shared__ int offn[BNODES + 1];
    __shared__ int cur[BNODES];

    int tid = threadIdx.x, lane = tid & 63, w = tid >> 6;
    int b = blockIdx.x;
    int n0 = b * BNODES;
    int e0 = boff[b], e1 = boff[b + 1];

    int c0 = 2 * lane;
    v2f w10 = { W1[c0],              W1[c0 + 1] };
    v2f w11 = { W1[HIDDEN + c0],     W1[HIDDEN + c0 + 1] };
    v2f w12 = { W1[2 * HIDDEN + c0], W1[2 * HIDDEN + c0 + 1] };
    v2f b1v = { b1[c0], b1[c0 + 1] };
    const v2f zero = { 0.f, 0.f };

    v2f acc[8];
    int dga[8];
    #pragma unroll
    for (int s = 0; s < 8; ++s) { acc[s] = zero; dga[s] = 0; }

    for (int cbeg = e0; cbeg < e1; cbeg += CAP) {
        int ccnt = e1 - cbeg; if (ccnt > CAP) ccnt = CAP;
        for (int i = tid; i < ccnt; i += 256) raw[i] = pairs[cbeg + i];
        if (tid < BNODES) cnt[tid] = 0;
        __syncthreads();
        for (int i = tid; i < ccnt; i += 256) atomicAdd(&cnt[raw[i] & 31u], 1);
        __syncthreads();
        if (tid < BNODES) {
            int v = cnt[tid];
            int sc = v;
            #pragma unroll
            for (int d = 1; d < BNODES; d <<= 1) {
                int u = __shfl_up(sc, d);
                if (lane >= d) sc += u;
            }
            offn[tid + 1] = sc;
            if (tid == 0) offn[0] = 0;
            cur[tid] = sc - v;  // exclusive
        }
        __syncthreads();
        for (int i = tid; i < ccnt; i += 256) {
            unsigned int r = raw[i];
            int j = (int)(r >> 5);
            int p = atomicAdd(&cur[r & 31u], 1);
            a_s[p] = x[j];
            const float2 pj = ((const float2*)pos)[j];
            p_s[p] = (v2f){ pj.x, pj.y };
        }
        __syncthreads();
        #pragma unroll
        for (int s = 0; s < 8; ++s) {
            int l = w * 8 + s;
            int sb = offn[l], se = offn[l + 1];
            if (sb < se) {
                float2 pi = ((const float2*)pos)[n0 + l];
                dga[s] += se - sb;
                // effective bias: b1 - px_i*w1row1 - py_i*w1row2
                v2f bb = b1v - pi.x * w11 - pi.y * w12;
                v2f A = acc[s];
                #pragma unroll 4
                for (int t = sb; t < se; ++t) {
                    float ae = a_s[t];
                    v2f pj = p_s[t];
                    v2f h = ae * w10 + bb;
                    h = pj.x * w11 + h;
                    h = pj.y * w12 + h;
                    h = __builtin_elementwise_max(h, zero);
                    A += h;
                }
                acc[s] = A;
            }
        }
        __syncthreads();
    }

    #pragma unroll
    for (int s = 0; s < 8; ++s) {
        int l = w * 8 + s;
        int node = n0 + l;
        if (node < N) {
            ((v2f*)&agg[(size_t)node * HIDDEN])[lane] = acc[s];
            if (lane == 0) deg[node] = dga[s];
        }
    }
}

// MFMA GEMM: out = agg @ W2 + deg*b2, in place on d_out (agg==out, f32).
// Each block: 64 rows (4 waves x 16). W2^T staged bf16 in LDS (pad 136).
// A-frags read f32 (own rows only -> in-place safe), converted bf16 in-register.
// mfma_f32_16x16x32_bf16 layouts: A: m=lane&15, k=(lane>>4)*8+j;
// B: n=lane&15, k=(lane>>4)*8+j; D: n=lane&15, m=(lane>>4)*4+i.
__global__ __launch_bounds__(256) void k_w2(float* __restrict__ agg,
                                            const float* __restrict__ W2,
                                            const float* __restrict__ b2,
                                            const int* __restrict__ deg, int N) {
    __shared__ unsigned short w2t[HIDDEN * W2LD];  // 34 KiB, W2^T[c][k]
    int tid = threadIdx.x;
    for (int idx = tid; idx < HIDDEN * HIDDEN; idx += 256) {
        int k = idx >> 7, c = idx & 127;            // idx = k*128 + c
        w2t[c * W2LD + k] = f2bf(W2[idx]);
    }
    __syncthreads();

    int lane = tid & 63, w = tid >> 6;
    int row0 = blockIdx.x * 64 + w * 16;
    if (row0 >= N) return;

    int rA = row0 + (lane & 15);
    int koff = (lane >> 4) * 8;
    bool okA = rA < N;

    // load + convert A-frags: a[k0][j] = agg[rA][k0*32 + koff + j]
    bf16x8 a[4];
    #pragma unroll
    for (int k0 = 0; k0 < 4; ++k0) {
        float4 fa = {0.f,0.f,0.f,0.f}, fb = {0.f,0.f,0.f,0.f};
        if (okA) {
            const float4* p = (const float4*)&agg[(size_t)rA * HIDDEN + k0 * 32 + koff];
            fa = p[0]; fb = p[1];
        }
        bf16x8 v;
        v[0] = (short)f2bf(fa.x); v[1] = (short)f2bf(fa.y);
        v[2] = (short)f2bf(fa.z); v[3] = (short)f2bf(fa.w);
        v[4] = (short)f2bf(fb.x); v[5] = (short)f2bf(fb.y);
        v[6] = (short)f2bf(fb.z); v[7] = (short)f2bf(fb.w);
        a[k0] = v;
    }

    f32x4 acc[8];
    #pragma unroll
    for (int ct = 0; ct < 8; ++ct) acc[ct] = (f32x4){0.f,0.f,0.f,0.f};

    #pragma unroll
    for (int ct = 0; ct < 8; ++ct) {
        int col = ct * 16 + (lane & 15);
        #pragma unroll
        for (int k0 = 0; k0 < 4; ++k0) {
            bf16x8 bfrag = *(const bf16x8*)&w2t[col * W2LD + k0 * 32 + koff];
            acc[ct] = __builtin_amdgcn_mfma_f32_16x16x32_bf16(a[k0], bfrag, acc[ct], 0, 0, 0);
        }
    }

    // epilogue: out[m][n] = acc + deg[m]*b2[n]
    int mbase = row0 + (lane >> 4) * 4;
    float dg[4];
    #pragma unroll
    for (int i = 0; i < 4; ++i) dg[i] = (mbase + i < N) ? (float)deg[mbase + i] : 0.f;

    #pragma unroll
    for (int ct = 0; ct < 8; ++ct) {
        int col = ct * 16 + (lane & 15);
        float b2c = b2[col];
        #pragma unroll
        for (int i = 0; i < 4; ++i) {
            int r = mbase + i;
            if (r < N) agg[(size_t)r * HIDDEN + col] = acc[ct][i] + dg[i] * b2c;
        }
    }
}

extern "C" void kernel_launch(void* const* d_in, const int* in_sizes, int n_in,
                              void* d_out, int out_size, void* d_ws, size_t ws_size,
                              hipStream_t stream) {
    const float* x   = (const float*)d_in[0];
    const float* pos = (const float*)d_in[1];
    const float* W1  = (const float*)d_in[2];
    const float* b1  = (const float*)d_in[3];
    const float* W2  = (const float*)d_in[4];
    const float* b2  = (const float*)d_in[5];
    const int*   ei  = (const int*)d_in[6];

    int N = in_sizes[0];        // x is [N,1]
    int E = in_sizes[6] / 2;    // edge_index is [2,E]
    const int* src = ei;
    const int* dst = ei + E;
    float* out = (float*)d_out;

    int NB = (N + BNODES - 1) / BNODES;

    // workspace: bcnt[NB] | boff[NB+1] | bcur[NB] | deg[N] | pairs[E]
    int* bcnt = (int*)d_ws;
    int* boff = bcnt + NB;
    int* bcur = boff + NB + 1;
    int* deg  = bcur + NB;
    unsigned int* pairs = (unsigned int*)(deg + N);

    int gribs = (E + EPB - 1) / EPB;

    k_zero<<<(NB + 255) / 256, 256, 0, stream>>>(bcnt, NB);
    k_bucket_hist<<<gribs, SThr, 0, stream>>>(dst, bcnt, E, NB);
    k_scan2<<<1, 1024, 0, stream>>>(bcnt, boff, bcur, NB, E);
    k_bucket_scatter<<<gribs, SThr, 0, stream>>>(src, dst, bcur, pairs, E, NB);
    k_main<<<NB, 256, 0, stream>>>(x, pos, W1, b1, boff, pairs, out, deg, N);
    k_w2<<<(N + 63) / 64, 256, 0, stream>>>(out, W2, b2, deg, N);
}